// Round 6
// baseline (3537.399 us; speedup 1.0000x reference)
//
#include <hip/hip_runtime.h>

// VGG_SMALL_1W1A on MI355X — R6.
// R5 post-mortem: arena overlap (AR placed inside AB after F doubled) corrupted
// both chains — NOT a numerics failure. R6: clean disjoint layout (93.3MB):
//   apk 4.7M | apkLo 4.7M | st 8K | Fhi 16.8M | Flo 16.8M | AB 16.8M | AR 16.8M | ARlo 16.8M
// Real branch is fully split-bf16: acts hi+lo, weights hi+lo (3-pass MFMA:
// Ahi.Whi + Alo.Whi + Ahi.Wlo), conv-out stored hi+lo -> per-layer error ~1e-5.
// Binary branch exact (sign acts/weights, int16 conv-out). X0 hi/lo acts live
// in the dead-until-stage-2 O_L2b / O_L2r regions of d_out (proven in R4).

typedef unsigned short u16;
typedef __attribute__((ext_vector_type(8))) short short8;
typedef __attribute__((ext_vector_type(8))) unsigned short ushort8;
typedef __attribute__((ext_vector_type(4))) unsigned short ushort4v;
typedef __attribute__((ext_vector_type(4))) float float4v;

__device__ __forceinline__ float bf2f(u16 u) { return __uint_as_float(((unsigned)u) << 16); }
__device__ __forceinline__ u16 f2bf(float f) {
    unsigned u = __float_as_uint(f);
    return (u16)((u + 0x7FFFu + ((u >> 16) & 1u)) >> 16);
}
__device__ __forceinline__ u16 lo_bf(float y, u16 hi) {  // bf16(y - fl(hi))
    return f2bf(y - bf2f(hi));
}
__device__ __forceinline__ u16 signbf(float y) {
    return y > 0.f ? 0x3F80u : (y < 0.f ? 0xBF80u : 0u);
}

// ---------------- conv0: 3->128, 32x32, direct fp32; STATS pass then APPLY pass ----------------
template <bool STATS>
__global__ __launch_bounds__(256) void conv0_kernel(const float* __restrict__ x,
                                                    const float* __restrict__ w0,
                                                    float* __restrict__ st,
                                                    const float* __restrict__ g,
                                                    const float* __restrict__ b,
                                                    u16* __restrict__ x0r,
                                                    u16* __restrict__ x0rlo,
                                                    u16* __restrict__ x0b) {
    __shared__ float xt[306];     // [ci][kh][w+2pad], 34-stride rows
    __shared__ float wl[3456];    // 128*27
    const int t = threadIdx.x;
    const int n = blockIdx.x >> 5;
    const int h = blockIdx.x & 31;
    for (int i = t; i < 306; i += 256) xt[i] = 0.f;
    for (int i = t; i < 3456; i += 256) wl[i] = w0[i];
    __syncthreads();
    for (int i = t; i < 288; i += 256) {
        int ci = i / 96; int rr = (i / 32) % 3; int w = i & 31;
        int gh = h - 1 + rr;
        if (gh >= 0 && gh < 32)
            xt[(ci * 3 + rr) * 34 + w + 1] = x[((n * 3 + ci) * 32 + gh) * 32 + w];
    }
    __syncthreads();
    const int w = t & 31, cg = t >> 5;
    float xin[27];
#pragma unroll
    for (int ci = 0; ci < 3; ci++)
#pragma unroll
        for (int r = 0; r < 3; r++)
#pragma unroll
            for (int kw = 0; kw < 3; kw++)
                xin[(ci * 3 + r) * 3 + kw] = xt[(ci * 3 + r) * 34 + w + kw];
    float accv[16];
#pragma unroll
    for (int j = 0; j < 16; j++) {
        int co = cg * 16 + j;
        float a = 0.f;
#pragma unroll
        for (int e = 0; e < 27; e++) a += xin[e] * wl[co * 27 + e];
        accv[j] = a;
    }
    if (STATS) {
#pragma unroll
        for (int j = 0; j < 16; j++) {
            float s = accv[j], q = accv[j] * accv[j];
#pragma unroll
            for (int off = 1; off < 32; off <<= 1) {
                s += __shfl_xor(s, off, 64);
                q += __shfl_xor(q, off, 64);
            }
            if (w == 0) {
                int co = cg * 16 + j;
                atomicAdd(&st[co], s);
                atomicAdd(&st[128 + co], q);
            }
        }
    } else {
        ushort8 r0, r1, l0, l1, s0, s1;
#pragma unroll
        for (int j = 0; j < 16; j++) {
            int co = cg * 16 + j;
            float mean = st[co] * (1.f / 131072.f);
            float var = st[128 + co] * (1.f / 131072.f) - mean * mean;
            var = fmaxf(var, 0.f);
            float scale = rsqrtf(var + 1e-5f) * g[co];
            float shift = b[co] - mean * scale;
            float y = fminf(fmaxf(accv[j] * scale + shift, -1.f), 1.f);
            u16 rv = f2bf(y), lv = lo_bf(y, rv), sv = signbf(y);
            if (j < 8) { r0[j] = rv; l0[j] = lv; s0[j] = sv; }
            else       { r1[j - 8] = rv; l1[j - 8] = lv; s1[j - 8] = sv; }
        }
        size_t o = ((size_t)(n * 1024 + h * 32 + w)) * 128 + cg * 16;
        if (x0r)   { *(ushort8*)(x0r + o) = r0;   *(ushort8*)(x0r + o + 8) = r1; }
        if (x0rlo) { *(ushort8*)(x0rlo + o) = l0; *(ushort8*)(x0rlo + o + 8) = l1; }
        if (x0b)   { *(ushort8*)(x0b + o) = s0;   *(ushort8*)(x0b + o + 8) = s1; }
    }
}

// ---------------- weight prepack; BIN = standardize+sign, else hi+lo split ----------------
template <bool BIN>
__global__ __launch_bounds__(256) void prepack_kernel(const float* __restrict__ w,
                                                      u16* __restrict__ apk,
                                                      u16* __restrict__ apkLo,
                                                      int Cin, int Cout) {
    const int t = threadIdx.x, o = blockIdx.x;
    const int E = Cin * 9;
    float m = 0.f;
    if (BIN) {
        float s = 0.f;
        for (int e = t; e < E; e += 256) s += w[o * E + e];
        __shared__ float Ls[256];
        Ls[t] = s;
        __syncthreads();
        for (int stp = 128; stp > 0; stp >>= 1) {
            if (t < stp) Ls[t] += Ls[t + stp];
            __syncthreads();
        }
        m = Ls[0] / (float)E;
    }
    const int CC = Cin >> 5, COT = Cout >> 7;
    for (int e = t; e < E; e += 256) {
        int ci = e / 9, tap = e % 9;
        float raw = w[o * E + e];
        int idx = ((tap * CC + (ci >> 5)) * COT + (o >> 7)) * 4096 + (o & 127) * 32 + (ci & 31);
        if (BIN) {
            apk[idx] = signbf(raw - m);
        } else {
            u16 hi = f2bf(raw);
            apk[idx] = hi;
            apkLo[idx] = lo_bf(raw, hi);
        }
    }
}

// ---------------- implicit-GEMM MFMA conv; BIN=1 pass, real=3-pass split-bf16 ----------------
// BIN: out = int16 exact. real: out = bf16 hi, outLo = bf16 lo (fp32-accurate pair).
template <bool POOL, bool BIN>
__global__ __launch_bounds__(256, 2) void conv_mfma_kernel(
    const u16* __restrict__ act, const u16* __restrict__ actLo,
    const u16* __restrict__ apk, const u16* __restrict__ apkLo,
    u16* __restrict__ out, u16* __restrict__ outLo,
    int Cin, int Cout, int H, int W) {
    const int HW = H * W;
    const int t = threadIdx.x;
    const int wave = t >> 6, lane = t & 63;
    const int l15 = lane & 15, quad = lane >> 4;
    const int wm = wave >> 1, wn = wave & 1;

    const int col0 = blockIdx.x * 128;
    const int cot = blockIdx.y;
    const int CC = Cin >> 5;
    const int COT = Cout >> 7;
    const bool two = (HW < 128);          // 128 cols span two images (HW==64)
    const int Wp = W + 2;
    const int nrows = two ? 2 * (H + 2) : (128 / W + 2);
    const int n0 = col0 / HW;
    const int h0 = two ? 0 : (col0 % HW) / W;

    __shared__ __align__(16) u16 As[4096];   // [co128][ci32]
    __shared__ __align__(16) u16 Bs[6528];   // [srow][wp][ci32]

    int bbase[4], gcol[4];
#pragma unroll
    for (int ni = 0; ni < 4; ni++) {
        int c = wn * 64 + ni * 16 + l15;
        int g = col0 + c;
        int n = g / HW; int hw = g % HW; int h = hw / W; int w = hw % W;
        gcol[ni] = g;
        int rb = two ? ((n - n0) * (H + 2) + h) : (h - h0);
        bbase[ni] = (rb * Wp + w) * 32 + quad * 8;
    }

    float4v acc[4][4];
    const float4v zf = {0.f, 0.f, 0.f, 0.f};
#pragma unroll
    for (int mi = 0; mi < 4; mi++)
#pragma unroll
        for (int ni = 0; ni < 4; ni++) acc[mi][ni] = zf;

    const int bgroups = nrows * Wp * 4;
    const size_t tapstride = (size_t)CC * COT * 4096;

    const int NP = BIN ? 1 : 3;
    for (int p = 0; p < NP; p++) {
        // pass 0: Ahi.Whi   pass 1: Alo.Whi   pass 2: Ahi.Wlo
        const u16* __restrict__ actp = (p == 1) ? actLo : act;
        const u16* __restrict__ apkp = (p == 2) ? apkLo : apk;
        for (int cc = 0; cc < CC; cc++) {
            __syncthreads();  // protect Bs from previous chunk's readers
            for (int idx = t; idx < bgroups; idx += 256) {
                int cig = idx & 3;
                int rest = idx >> 2;
                int wp = rest % Wp;
                int srow = rest / Wp;
                int n, gh;
                if (two) { n = n0 + srow / (H + 2); gh = srow % (H + 2) - 1; }
                else     { n = n0; gh = h0 + srow - 1; }
                int gw = wp - 1;
                short8 v = {0, 0, 0, 0, 0, 0, 0, 0};
                if (gh >= 0 && gh < H && gw >= 0 && gw < W) {
                    const u16* ptr = actp + ((size_t)(n * HW + gh * W + gw)) * Cin + cc * 32 + cig * 8;
                    v = *(const short8*)ptr;
                }
                *(short8*)&Bs[(srow * Wp + wp) * 32 + cig * 8] = v;
            }
            const u16* abase = apkp + ((size_t)(cc * COT + cot)) * 4096;
            for (int tap = 0; tap < 9; tap++) {
                __syncthreads();  // protect As; also covers Bs writes before tap 0
                {
                    const u16* ab = abase + (size_t)tap * tapstride;
                    *(short8*)&As[t * 8] = *(const short8*)(ab + t * 8);
                    *(short8*)&As[2048 + t * 8] = *(const short8*)(ab + 2048 + t * 8);
                }
                __syncthreads();
                const int kh = tap / 3, kw = tap % 3;
                const int boff = (kh * Wp + kw) * 32;
                short8 afr[4], bfr[4];
#pragma unroll
                for (int mi = 0; mi < 4; mi++)
                    afr[mi] = *(const short8*)&As[(wm * 64 + mi * 16 + l15) * 32 + quad * 8];
#pragma unroll
                for (int ni = 0; ni < 4; ni++)
                    bfr[ni] = *(const short8*)&Bs[bbase[ni] + boff];
#pragma unroll
                for (int mi = 0; mi < 4; mi++)
#pragma unroll
                    for (int ni = 0; ni < 4; ni++)
                        acc[mi][ni] = __builtin_amdgcn_mfma_f32_16x16x32_bf16(
                            afr[mi], bfr[ni], acc[mi][ni], 0, 0, 0);
            }
        }
    }

    const int cobase = cot * 128 + wm * 64 + quad * 4;
    // store helper: BIN -> int16 exact; real -> bf16 hi + bf16 lo
    auto store4 = [&](size_t off, float4v v) {
        if (BIN) {
            ushort4v r;
#pragma unroll
            for (int k = 0; k < 4; k++) r[k] = (u16)(short)(int)v[k];
            *(ushort4v*)(out + off) = r;
        } else {
            ushort4v hi, lo;
#pragma unroll
            for (int k = 0; k < 4; k++) {
                hi[k] = f2bf(v[k]);
                lo[k] = lo_bf(v[k], hi[k]);
            }
            *(ushort4v*)(out + off) = hi;
            *(ushort4v*)(outLo + off) = lo;
        }
    };

    if (!POOL) {
#pragma unroll
        for (int mi = 0; mi < 4; mi++)
#pragma unroll
            for (int ni = 0; ni < 4; ni++)
                store4((size_t)gcol[ni] * Cout + cobase + mi * 16, acc[mi][ni]);
    } else {
        const int pH = H >> 1, pW = W >> 1;
        if (W == 32) {
#pragma unroll
            for (int mi = 0; mi < 4; mi++)
#pragma unroll
                for (int nip = 0; nip < 2; nip++) {
                    float4v v;
#pragma unroll
                    for (int k = 0; k < 4; k++)
                        v[k] = fmaxf((float)acc[mi][nip][k], (float)acc[mi][nip + 2][k]);
#pragma unroll
                    for (int k = 0; k < 4; k++) {
                        float vv = v[k];
                        v[k] = fmaxf(vv, __shfl_xor(vv, 1, 64));
                    }
                    if ((l15 & 1) == 0) {
                        int pw = nip * 8 + (l15 >> 1);
                        int ph = (h0 >> 1) + wn;
                        int prow = (n0 * pH + ph) * pW + pw;
                        store4((size_t)prow * Cout + cobase + mi * 16, v);
                    }
                }
        } else if (W == 16) {
#pragma unroll
            for (int mi = 0; mi < 4; mi++)
#pragma unroll
                for (int nip = 0; nip < 4; nip += 2) {
                    float4v v;
#pragma unroll
                    for (int k = 0; k < 4; k++)
                        v[k] = fmaxf((float)acc[mi][nip][k], (float)acc[mi][nip + 1][k]);
#pragma unroll
                    for (int k = 0; k < 4; k++) {
                        float vv = v[k];
                        v[k] = fmaxf(vv, __shfl_xor(vv, 1, 64));
                    }
                    if ((l15 & 1) == 0) {
                        int pw = l15 >> 1;
                        int ph = (h0 + wn * 4 + nip) >> 1;
                        int prow = (n0 * pH + ph) * pW + pw;
                        store4((size_t)prow * Cout + cobase + mi * 16, v);
                    }
                }
        } else {  // W == 8, two-image: n = n0 + wn, h = ni*2 + (l15>>3), w = l15&7
#pragma unroll
            for (int mi = 0; mi < 4; mi++)
#pragma unroll
                for (int ni = 0; ni < 4; ni++) {
                    float4v v = acc[mi][ni];
#pragma unroll
                    for (int k = 0; k < 4; k++) {
                        float vv = v[k];
                        vv = fmaxf(vv, __shfl_xor(vv, 1, 64));
                        v[k] = fmaxf(vv, __shfl_xor(vv, 8, 64));
                    }
                    if ((l15 & 9) == 0) {
                        int pw = l15 >> 1;
                        int ph = ni;
                        int n = n0 + wn;
                        int prow = (n * pH + ph) * pW + pw;
                        store4((size_t)prow * Cout + cobase + mi * 16, v);
                    }
                }
        }
    }
}

// ---------------- per-channel batch stats (sum, sumsq); BIN=int16, real=hi+lo ----------------
template <bool BIN>
__global__ __launch_bounds__(256) void stats_kernel(const u16* __restrict__ src,
                                                    const u16* __restrict__ srcLo,
                                                    float* __restrict__ st,
                                                    int C, int rows_per_block) {
    const int t = threadIdx.x;
    const int c = blockIdx.x * 64 + (t & 63);
    const int rg = t >> 6;
    const int r0 = blockIdx.y * rows_per_block;
    float s = 0.f, q = 0.f;
    for (int r = r0 + rg; r < r0 + rows_per_block; r += 4) {
        size_t i = (size_t)r * C + c;
        float v = BIN ? (float)(short)src[i] : (bf2f(src[i]) + bf2f(srcLo[i]));
        s += v;
        q += v * v;
    }
    __shared__ float Ls[256], Lq[256];
    Ls[t] = s; Lq[t] = q;
    __syncthreads();
    if (t < 64) {
        s = Ls[t] + Ls[t + 64] + Ls[t + 128] + Ls[t + 192];
        q = Lq[t] + Lq[t + 64] + Lq[t + 128] + Lq[t + 192];
        atomicAdd(&st[c], s);
        atomicAdd(&st[C + c], q);
    }
}

// ---------------- BN + hardtanh; acts (mode 1=real hi+lo, 2=sign) + fp32 NCHW d_out ----------------
template <bool BIN>
__global__ __launch_bounds__(256) void bn_apply_kernel(const u16* __restrict__ src,
                                                       const u16* __restrict__ srcLo,
                                                       int C, int HW,
                                                       const float* __restrict__ st, float cntinv,
                                                       const float* __restrict__ g,
                                                       const float* __restrict__ b,
                                                       float* __restrict__ dout,
                                                       float* __restrict__ dout2,
                                                       u16* __restrict__ act,
                                                       u16* __restrict__ actLo,
                                                       int act_mode) {
    const int t = threadIdx.x;
    const int cl = t & 63, rl = t >> 6;
    const int c = blockIdx.y * 64 + cl;
    const float mean = st[c] * cntinv;
    float var = st[C + c] * cntinv - mean * mean;
    var = fmaxf(var, 0.f);
    const float scale = rsqrtf(var + 1e-5f) * g[c];
    const float shift = b[c] - mean * scale;
    __shared__ float T[64][65];
#pragma unroll
    for (int i = 0; i < 16; i++) {
        int rlocal = rl + i * 4;
        int row = blockIdx.x * 64 + rlocal;
        size_t idx = (size_t)row * C + c;
        float v = BIN ? (float)(short)src[idx] : (bf2f(src[idx]) + bf2f(srcLo[idx]));
        float y = fminf(fmaxf(v * scale + shift, -1.f), 1.f);
        if (act_mode == 1) {
            u16 hi = f2bf(y);
            act[idx] = hi;
            actLo[idx] = lo_bf(y, hi);
        } else if (act_mode == 2) {
            act[idx] = signbf(y);
        }
        T[rlocal][cl] = y;
    }
    __syncthreads();
#pragma unroll
    for (int i = 0; i < 16; i++) {
        int clocal = rl + i * 4;
        int cg = blockIdx.y * 64 + clocal;
        int rglob = blockIdx.x * 64 + cl;
        int n = rglob / HW, hw = rglob % HW;
        size_t o = ((size_t)n * C + cg) * HW + hw;
        float val = T[cl][clocal];
        dout[o] = val;
        if (dout2) dout2[o] = val;
    }
}

// ---------------- FC: [128,8192] @ [10,8192]^T + b (all fp32) ----------------
__global__ __launch_bounds__(256) void fc_kernel(const float* __restrict__ penul,
                                                 const float* __restrict__ fcw,
                                                 const float* __restrict__ fcb,
                                                 float* __restrict__ out) {
    const int t = threadIdx.x, n = blockIdx.x;
    float acc[10];
#pragma unroll
    for (int j = 0; j < 10; j++) acc[j] = 0.f;
    for (int i = t; i < 8192; i += 256) {
        float p = penul[n * 8192 + i];
#pragma unroll
        for (int j = 0; j < 10; j++) acc[j] += p * fcw[j * 8192 + i];
    }
    __shared__ float L[10][256];
#pragma unroll
    for (int j = 0; j < 10; j++) L[j][t] = acc[j];
    __syncthreads();
    for (int s = 128; s > 0; s >>= 1) {
        if (t < s) {
#pragma unroll
            for (int j = 0; j < 10; j++) L[j][t] += L[j][t + s];
        }
        __syncthreads();
    }
    if (t < 10) out[n * 10 + t] = L[t][0] + fcb[t];
}

extern "C" void kernel_launch(void* const* d_in, const int* in_sizes, int n_in,
                              void* d_out, int out_size, void* d_ws, size_t ws_size,
                              hipStream_t stream) {
    (void)in_sizes; (void)n_in; (void)out_size; (void)ws_size;

    const float* X = (const float*)d_in[0];
    const float* W0 = (const float*)d_in[1];
    const float* Wl[5] = {(const float*)d_in[2], (const float*)d_in[3], (const float*)d_in[4],
                          (const float*)d_in[5], (const float*)d_in[6]};
    const float* FCW = (const float*)d_in[7];
    const float* FCB = (const float*)d_in[8];
    const float* G[6]; const float* Bb[6];
    for (int i = 0; i < 6; i++) { G[i] = (const float*)d_in[9 + 2 * i]; Bb[i] = (const float*)d_in[10 + 2 * i]; }

    float* OUT = (float*)d_out;
    char* ws = (char*)d_ws;

    // ws layout (bytes), all disjoint, total 93,329,408:
    u16* apk   = (u16*)(ws);               // [0,          4,718,592)
    u16* apkLo = (u16*)(ws + 4718592);     // [4,718,592,  9,437,184)
    float* st0 = (float*)(ws + 9437184);   // [9,437,184,  9,439,232)
    float* stk = (float*)(ws + 9439232);   // [9,439,232,  9,443,328)
    u16* F     = (u16*)(ws + 9443328);     // [9,443,328,  26,220,544)  8,388,608 elems (hi / int16)
    u16* Flo   = (u16*)(ws + 26220544);    // [26,220,544, 42,997,760)  8,388,608 elems (lo, real)
    u16* AB    = (u16*)(ws + 42997760);    // [42,997,760, 59,774,976)  8,388,608 elems
    u16* AR    = (u16*)(ws + 59774976);    // [59,774,976, 76,552,192)  8,388,608 elems
    u16* ARlo  = (u16*)(ws + 76552192);    // [76,552,192, 93,329,408)  8,388,608 elems

    // x0 hi acts -> dead-until-stage-2 O_L2b float region; x0 lo -> O_L2r region.
    u16* X0   = (u16*)(OUT + 9438464);     // 16,777,216 u16 = O_L2b floats exactly
    u16* X0lo = (u16*)(OUT + 17827072);    // 16,777,216 u16 = O_L2r floats exactly

    float* O_out = OUT;
    float* O_pen = OUT + 1280;
    float* O_L1b = OUT + 1049856;
    float* O_L1r = OUT + 5244160;
    float* O_L2b = OUT + 9438464;
    float* O_L2r = OUT + 17827072;
    float* O_L3b = OUT + 26215680;
    float* O_L3r = OUT + 28312832;
    float* O_L4b = OUT + 30409984;
    float* O_L4r = OUT + 34604288;
    float* O_L5b = OUT + 38798592;
    float* O_L5r = OUT + 39847168;

    // ---- stage 0: conv0 stats; apply (sign acts) -> X0
    hipMemsetAsync(st0, 0, 2048, stream);
    conv0_kernel<true><<<4096, 256, 0, stream>>>(X, W0, st0, G[0], Bb[0], nullptr, nullptr, nullptr);
    conv0_kernel<false><<<4096, 256, 0, stream>>>(X, W0, st0, G[0], Bb[0], nullptr, nullptr, X0);

    struct Stage {
        const float* w; int Cin, Cout, H, W; bool pool;
        dim3 cgrid; dim3 sgrid; int srpb; dim3 bgrid; int bHW; float cntinv;
        float* db; float* dr;
    };
    const Stage S[5] = {
        {Wl[0], 128, 128, 32, 32, true,  dim3(1024, 1), dim3(2, 64), 512, dim3(512, 2), 256, 1.f / 32768.f, O_L1b, O_L1r},
        {Wl[1], 128, 256, 16, 16, false, dim3(256, 2),  dim3(4, 64), 512, dim3(512, 4), 256, 1.f / 32768.f, O_L2b, O_L2r},
        {Wl[2], 256, 256, 16, 16, true,  dim3(256, 2),  dim3(4, 16), 512, dim3(128, 4), 64,  1.f / 8192.f,  O_L3b, O_L3r},
        {Wl[3], 256, 512, 8, 8,   false, dim3(64, 4),   dim3(8, 16), 512, dim3(128, 8), 64,  1.f / 8192.f,  O_L4b, O_L4r},
        {Wl[4], 512, 512, 8, 8,   true,  dim3(64, 4),   dim3(8, 16), 128, dim3(32, 8),  16,  1.f / 2048.f,  O_L5b, O_L5r},
    };

    for (int k = 0; k < 5; k++) {
        const Stage& s = S[k];
        const u16* inB = (k == 0) ? X0 : AB;
        const u16* inR = (k == 0) ? X0 : AR;
        const u16* inRlo = (k == 0) ? X0lo : ARlo;

        // ---- binary branch (exact: sign weights/acts, int16 conv-out)
        prepack_kernel<true><<<s.Cout, 256, 0, stream>>>(s.w, apk, nullptr, s.Cin, s.Cout);
        if (s.pool) conv_mfma_kernel<true, true><<<s.cgrid, 256, 0, stream>>>(inB, nullptr, apk, nullptr, F, nullptr, s.Cin, s.Cout, s.H, s.W);
        else        conv_mfma_kernel<false, true><<<s.cgrid, 256, 0, stream>>>(inB, nullptr, apk, nullptr, F, nullptr, s.Cin, s.Cout, s.H, s.W);
        hipMemsetAsync(stk, 0, 4096, stream);
        stats_kernel<true><<<s.sgrid, 256, 0, stream>>>(F, nullptr, stk, s.Cout, s.srpb);
        bn_apply_kernel<true><<<s.bgrid, 256, 0, stream>>>(F, nullptr, s.Cout, s.bHW, stk, s.cntinv,
                                                           G[k + 1], Bb[k + 1], s.db,
                                                           (k == 4) ? O_pen : nullptr,
                                                           AB, nullptr, (k == 4) ? 0 : 2);

        // regenerate x0r (hi+lo) into X0/X0lo after the binary stage-1 conv consumed x0b
        if (k == 0)
            conv0_kernel<false><<<4096, 256, 0, stream>>>(X, W0, st0, G[0], Bb[0], X0, X0lo, nullptr);

        // ---- real branch (3-pass split-bf16; conv-out stored hi+lo)
        prepack_kernel<false><<<s.Cout, 256, 0, stream>>>(s.w, apk, apkLo, s.Cin, s.Cout);
        if (s.pool) conv_mfma_kernel<true, false><<<s.cgrid, 256, 0, stream>>>(inR, inRlo, apk, apkLo, F, Flo, s.Cin, s.Cout, s.H, s.W);
        else        conv_mfma_kernel<false, false><<<s.cgrid, 256, 0, stream>>>(inR, inRlo, apk, apkLo, F, Flo, s.Cin, s.Cout, s.H, s.W);
        hipMemsetAsync(stk, 0, 4096, stream);
        stats_kernel<false><<<s.sgrid, 256, 0, stream>>>(F, Flo, stk, s.Cout, s.srpb);
        bn_apply_kernel<false><<<s.bgrid, 256, 0, stream>>>(F, Flo, s.Cout, s.bHW, stk, s.cntinv,
                                                            G[k + 1], Bb[k + 1], s.dr, nullptr,
                                                            AR, ARlo, (k == 4) ? 0 : 1);
    }

    // ---- fc
    fc_kernel<<<128, 256, 0, stream>>>(O_pen, FCW, FCB, O_out);
}

// Round 8
// 1934.667 us; speedup vs baseline: 1.8284x; 1.8284x over previous
//
#include <hip/hip_runtime.h>

// VGG_SMALL_1W1A on MI355X — R8.
// R7 post-mortem: C0 (fp32 conv0-out in d_out) overlapped X0's O_L2b home —
// bn0_apply read C0 while other blocks wrote X0 into C0's second half ->
// corrupted sign acts -> binary chain off (logits absmax 3.04). R8: C0 moved
// to ws at the F..AR arenas (67.1MB, dead until stage 1 — exact fit). All
// other pointers/kernels byte-identical to R7 (stage-0 restructure that
// removes the 1584us conv0 atomic stall from R6).

typedef unsigned short u16;
typedef __attribute__((ext_vector_type(8))) short short8;
typedef __attribute__((ext_vector_type(8))) unsigned short ushort8;
typedef __attribute__((ext_vector_type(4))) unsigned short ushort4v;
typedef __attribute__((ext_vector_type(4))) float float4v;

__device__ __forceinline__ float bf2f(u16 u) { return __uint_as_float(((unsigned)u) << 16); }
__device__ __forceinline__ u16 f2bf(float f) {
    unsigned u = __float_as_uint(f);
    return (u16)((u + 0x7FFFu + ((u >> 16) & 1u)) >> 16);
}
__device__ __forceinline__ u16 lo_bf(float y, u16 hi) {  // bf16(y - fl(hi))
    return f2bf(y - bf2f(hi));
}
__device__ __forceinline__ u16 signbf(float y) {
    return y > 0.f ? 0x3F80u : (y < 0.f ? 0xBF80u : 0u);
}

// ---------------- conv0_main: 3->128, 32x32, direct fp32, fp32 NHWC out ----------------
__global__ __launch_bounds__(256) void conv0_main(const float* __restrict__ x,
                                                  const float* __restrict__ w0,
                                                  float* __restrict__ out) {
    __shared__ float xt[306];     // [ci][kh][w+2pad], 34-stride rows
    __shared__ float wl[3456];    // 128*27
    const int t = threadIdx.x;
    const int n = blockIdx.x >> 5;
    const int h = blockIdx.x & 31;
    for (int i = t; i < 306; i += 256) xt[i] = 0.f;
    for (int i = t; i < 3456; i += 256) wl[i] = w0[i];
    __syncthreads();
    for (int i = t; i < 288; i += 256) {
        int ci = i / 96; int rr = (i / 32) % 3; int w = i & 31;
        int gh = h - 1 + rr;
        if (gh >= 0 && gh < 32)
            xt[(ci * 3 + rr) * 34 + w + 1] = x[((n * 3 + ci) * 32 + gh) * 32 + w];
    }
    __syncthreads();
    const int w = t & 31, cg = t >> 5;
    float xin[27];
#pragma unroll
    for (int ci = 0; ci < 3; ci++)
#pragma unroll
        for (int r = 0; r < 3; r++)
#pragma unroll
            for (int kw = 0; kw < 3; kw++)
                xin[(ci * 3 + r) * 3 + kw] = xt[(ci * 3 + r) * 34 + w + kw];
    float* o = out + ((size_t)(n * 1024 + h * 32 + w)) * 128 + cg * 16;
#pragma unroll
    for (int jq = 0; jq < 4; jq++) {
        float4v v;
#pragma unroll
        for (int jk = 0; jk < 4; jk++) {
            int co = cg * 16 + jq * 4 + jk;
            float a = 0.f;
#pragma unroll
            for (int e = 0; e < 27; e++) a += xin[e] * wl[co * 27 + e];
            v[jk] = a;
        }
        *(float4v*)(o + jq * 4) = v;
    }
}

// ---------------- stats over fp32 NHWC (stage 0) ----------------
__global__ __launch_bounds__(256) void stats0_kernel(const float* __restrict__ src,
                                                     float* __restrict__ st,
                                                     int C, int rows_per_block) {
    const int t = threadIdx.x;
    const int c = blockIdx.x * 64 + (t & 63);
    const int rg = t >> 6;
    const int r0 = blockIdx.y * rows_per_block;
    float s = 0.f, q = 0.f;
    for (int r = r0 + rg; r < r0 + rows_per_block; r += 4) {
        float v = src[(size_t)r * C + c];
        s += v;
        q += v * v;
    }
    __shared__ float Ls[256], Lq[256];
    Ls[t] = s; Lq[t] = q;
    __syncthreads();
    if (t < 64) {
        s = Ls[t] + Ls[t + 64] + Ls[t + 128] + Ls[t + 192];
        q = Lq[t] + Lq[t + 64] + Lq[t + 128] + Lq[t + 192];
        atomicAdd(&st[c], s);
        atomicAdd(&st[C + c], q);
    }
}

// ---------------- bn0_apply: fp32 conv0-out -> sign acts + real hi/lo acts ----------------
__global__ __launch_bounds__(256) void bn0_apply(const float* __restrict__ src,
                                                 const float* __restrict__ st,
                                                 const float* __restrict__ g,
                                                 const float* __restrict__ b,
                                                 u16* __restrict__ sg,
                                                 u16* __restrict__ hi,
                                                 u16* __restrict__ lo) {
    const int t = threadIdx.x;
    __shared__ float sc[128], sh[128];
    if (t < 128) {
        float mean = st[t] * (1.f / 131072.f);
        float var = fmaxf(st[128 + t] * (1.f / 131072.f) - mean * mean, 0.f);
        float scale = rsqrtf(var + 1e-5f) * g[t];
        sc[t] = scale;
        sh[t] = b[t] - mean * scale;
    }
    __syncthreads();
    size_t i = ((size_t)blockIdx.x * 256 + t) * 4;
    int c0 = (int)(i & 127);
    float4v v = *(const float4v*)(src + i);
    ushort4v hv, lv, sv;
#pragma unroll
    for (int k = 0; k < 4; k++) {
        float y = fminf(fmaxf(v[k] * sc[c0 + k] + sh[c0 + k], -1.f), 1.f);
        hv[k] = f2bf(y);
        lv[k] = lo_bf(y, hv[k]);
        sv[k] = signbf(y);
    }
    *(ushort4v*)(sg + i) = sv;
    *(ushort4v*)(hi + i) = hv;
    *(ushort4v*)(lo + i) = lv;
}

// ---------------- weight prepack; BIN = standardize+sign, else hi+lo split ----------------
template <bool BIN>
__global__ __launch_bounds__(256) void prepack_kernel(const float* __restrict__ w,
                                                      u16* __restrict__ apk,
                                                      u16* __restrict__ apkLo,
                                                      int Cin, int Cout) {
    const int t = threadIdx.x, o = blockIdx.x;
    const int E = Cin * 9;
    float m = 0.f;
    if (BIN) {
        float s = 0.f;
        for (int e = t; e < E; e += 256) s += w[o * E + e];
        __shared__ float Ls[256];
        Ls[t] = s;
        __syncthreads();
        for (int stp = 128; stp > 0; stp >>= 1) {
            if (t < stp) Ls[t] += Ls[t + stp];
            __syncthreads();
        }
        m = Ls[0] / (float)E;
    }
    const int CC = Cin >> 5, COT = Cout >> 7;
    for (int e = t; e < E; e += 256) {
        int ci = e / 9, tap = e % 9;
        float raw = w[o * E + e];
        int idx = ((tap * CC + (ci >> 5)) * COT + (o >> 7)) * 4096 + (o & 127) * 32 + (ci & 31);
        if (BIN) {
            apk[idx] = signbf(raw - m);
        } else {
            u16 hi = f2bf(raw);
            apk[idx] = hi;
            apkLo[idx] = lo_bf(raw, hi);
        }
    }
}

// ---------------- implicit-GEMM MFMA conv; BIN=1 pass, real=3-pass split-bf16 ----------------
// BIN: out = int16 exact. real: out = bf16 hi, outLo = bf16 lo (fp32-accurate pair).
template <bool POOL, bool BIN>
__global__ __launch_bounds__(256, 2) void conv_mfma_kernel(
    const u16* __restrict__ act, const u16* __restrict__ actLo,
    const u16* __restrict__ apk, const u16* __restrict__ apkLo,
    u16* __restrict__ out, u16* __restrict__ outLo,
    int Cin, int Cout, int H, int W) {
    const int HW = H * W;
    const int t = threadIdx.x;
    const int wave = t >> 6, lane = t & 63;
    const int l15 = lane & 15, quad = lane >> 4;
    const int wm = wave >> 1, wn = wave & 1;

    const int col0 = blockIdx.x * 128;
    const int cot = blockIdx.y;
    const int CC = Cin >> 5;
    const int COT = Cout >> 7;
    const bool two = (HW < 128);          // 128 cols span two images (HW==64)
    const int Wp = W + 2;
    const int nrows = two ? 2 * (H + 2) : (128 / W + 2);
    const int n0 = col0 / HW;
    const int h0 = two ? 0 : (col0 % HW) / W;

    __shared__ __align__(16) u16 As[4096];   // [co128][ci32]
    __shared__ __align__(16) u16 Bs[6528];   // [srow][wp][ci32]

    int bbase[4], gcol[4];
#pragma unroll
    for (int ni = 0; ni < 4; ni++) {
        int c = wn * 64 + ni * 16 + l15;
        int g = col0 + c;
        int n = g / HW; int hw = g % HW; int h = hw / W; int w = hw % W;
        gcol[ni] = g;
        int rb = two ? ((n - n0) * (H + 2) + h) : (h - h0);
        bbase[ni] = (rb * Wp + w) * 32 + quad * 8;
    }

    float4v acc[4][4];
    const float4v zf = {0.f, 0.f, 0.f, 0.f};
#pragma unroll
    for (int mi = 0; mi < 4; mi++)
#pragma unroll
        for (int ni = 0; ni < 4; ni++) acc[mi][ni] = zf;

    const int bgroups = nrows * Wp * 4;
    const size_t tapstride = (size_t)CC * COT * 4096;

    const int NP = BIN ? 1 : 3;
    for (int p = 0; p < NP; p++) {
        // pass 0: Ahi.Whi   pass 1: Alo.Whi   pass 2: Ahi.Wlo
        const u16* __restrict__ actp = (p == 1) ? actLo : act;
        const u16* __restrict__ apkp = (p == 2) ? apkLo : apk;
        for (int cc = 0; cc < CC; cc++) {
            __syncthreads();  // protect Bs from previous chunk's readers
            for (int idx = t; idx < bgroups; idx += 256) {
                int cig = idx & 3;
                int rest = idx >> 2;
                int wp = rest % Wp;
                int srow = rest / Wp;
                int n, gh;
                if (two) { n = n0 + srow / (H + 2); gh = srow % (H + 2) - 1; }
                else     { n = n0; gh = h0 + srow - 1; }
                int gw = wp - 1;
                short8 v = {0, 0, 0, 0, 0, 0, 0, 0};
                if (gh >= 0 && gh < H && gw >= 0 && gw < W) {
                    const u16* ptr = actp + ((size_t)(n * HW + gh * W + gw)) * Cin + cc * 32 + cig * 8;
                    v = *(const short8*)ptr;
                }
                *(short8*)&Bs[(srow * Wp + wp) * 32 + cig * 8] = v;
            }
            const u16* abase = apkp + ((size_t)(cc * COT + cot)) * 4096;
            for (int tap = 0; tap < 9; tap++) {
                __syncthreads();  // protect As; also covers Bs writes before tap 0
                {
                    const u16* ab = abase + (size_t)tap * tapstride;
                    *(short8*)&As[t * 8] = *(const short8*)(ab + t * 8);
                    *(short8*)&As[2048 + t * 8] = *(const short8*)(ab + 2048 + t * 8);
                }
                __syncthreads();
                const int kh = tap / 3, kw = tap % 3;
                const int boff = (kh * Wp + kw) * 32;
                short8 afr[4], bfr[4];
#pragma unroll
                for (int mi = 0; mi < 4; mi++)
                    afr[mi] = *(const short8*)&As[(wm * 64 + mi * 16 + l15) * 32 + quad * 8];
#pragma unroll
                for (int ni = 0; ni < 4; ni++)
                    bfr[ni] = *(const short8*)&Bs[bbase[ni] + boff];
#pragma unroll
                for (int mi = 0; mi < 4; mi++)
#pragma unroll
                    for (int ni = 0; ni < 4; ni++)
                        acc[mi][ni] = __builtin_amdgcn_mfma_f32_16x16x32_bf16(
                            afr[mi], bfr[ni], acc[mi][ni], 0, 0, 0);
            }
        }
    }

    const int cobase = cot * 128 + wm * 64 + quad * 4;
    // store helper: BIN -> int16 exact; real -> bf16 hi + bf16 lo
    auto store4 = [&](size_t off, float4v v) {
        if (BIN) {
            ushort4v r;
#pragma unroll
            for (int k = 0; k < 4; k++) r[k] = (u16)(short)(int)v[k];
            *(ushort4v*)(out + off) = r;
        } else {
            ushort4v hi, lo;
#pragma unroll
            for (int k = 0; k < 4; k++) {
                hi[k] = f2bf(v[k]);
                lo[k] = lo_bf(v[k], hi[k]);
            }
            *(ushort4v*)(out + off) = hi;
            *(ushort4v*)(outLo + off) = lo;
        }
    };

    if (!POOL) {
#pragma unroll
        for (int mi = 0; mi < 4; mi++)
#pragma unroll
            for (int ni = 0; ni < 4; ni++)
                store4((size_t)gcol[ni] * Cout + cobase + mi * 16, acc[mi][ni]);
    } else {
        const int pH = H >> 1, pW = W >> 1;
        if (W == 32) {
#pragma unroll
            for (int mi = 0; mi < 4; mi++)
#pragma unroll
                for (int nip = 0; nip < 2; nip++) {
                    float4v v;
#pragma unroll
                    for (int k = 0; k < 4; k++)
                        v[k] = fmaxf((float)acc[mi][nip][k], (float)acc[mi][nip + 2][k]);
#pragma unroll
                    for (int k = 0; k < 4; k++) {
                        float vv = v[k];
                        v[k] = fmaxf(vv, __shfl_xor(vv, 1, 64));
                    }
                    if ((l15 & 1) == 0) {
                        int pw = nip * 8 + (l15 >> 1);
                        int ph = (h0 >> 1) + wn;
                        int prow = (n0 * pH + ph) * pW + pw;
                        store4((size_t)prow * Cout + cobase + mi * 16, v);
                    }
                }
        } else if (W == 16) {
#pragma unroll
            for (int mi = 0; mi < 4; mi++)
#pragma unroll
                for (int nip = 0; nip < 4; nip += 2) {
                    float4v v;
#pragma unroll
                    for (int k = 0; k < 4; k++)
                        v[k] = fmaxf((float)acc[mi][nip][k], (float)acc[mi][nip + 1][k]);
#pragma unroll
                    for (int k = 0; k < 4; k++) {
                        float vv = v[k];
                        v[k] = fmaxf(vv, __shfl_xor(vv, 1, 64));
                    }
                    if ((l15 & 1) == 0) {
                        int pw = l15 >> 1;
                        int ph = (h0 + wn * 4 + nip) >> 1;
                        int prow = (n0 * pH + ph) * pW + pw;
                        store4((size_t)prow * Cout + cobase + mi * 16, v);
                    }
                }
        } else {  // W == 8, two-image: n = n0 + wn, h = ni*2 + (l15>>3), w = l15&7
#pragma unroll
            for (int mi = 0; mi < 4; mi++)
#pragma unroll
                for (int ni = 0; ni < 4; ni++) {
                    float4v v = acc[mi][ni];
#pragma unroll
                    for (int k = 0; k < 4; k++) {
                        float vv = v[k];
                        vv = fmaxf(vv, __shfl_xor(vv, 1, 64));
                        v[k] = fmaxf(vv, __shfl_xor(vv, 8, 64));
                    }
                    if ((l15 & 9) == 0) {
                        int pw = l15 >> 1;
                        int ph = ni;
                        int n = n0 + wn;
                        int prow = (n * pH + ph) * pW + pw;
                        store4((size_t)prow * Cout + cobase + mi * 16, v);
                    }
                }
        }
    }
}

// ---------------- per-channel batch stats (sum, sumsq); BIN=int16, real=hi+lo ----------------
template <bool BIN>
__global__ __launch_bounds__(256) void stats_kernel(const u16* __restrict__ src,
                                                    const u16* __restrict__ srcLo,
                                                    float* __restrict__ st,
                                                    int C, int rows_per_block) {
    const int t = threadIdx.x;
    const int c = blockIdx.x * 64 + (t & 63);
    const int rg = t >> 6;
    const int r0 = blockIdx.y * rows_per_block;
    float s = 0.f, q = 0.f;
    for (int r = r0 + rg; r < r0 + rows_per_block; r += 4) {
        size_t i = (size_t)r * C + c;
        float v = BIN ? (float)(short)src[i] : (bf2f(src[i]) + bf2f(srcLo[i]));
        s += v;
        q += v * v;
    }
    __shared__ float Ls[256], Lq[256];
    Ls[t] = s; Lq[t] = q;
    __syncthreads();
    if (t < 64) {
        s = Ls[t] + Ls[t + 64] + Ls[t + 128] + Ls[t + 192];
        q = Lq[t] + Lq[t + 64] + Lq[t + 128] + Lq[t + 192];
        atomicAdd(&st[c], s);
        atomicAdd(&st[C + c], q);
    }
}

// ---------------- BN + hardtanh; acts (mode 1=real hi+lo, 2=sign) + fp32 NCHW d_out ----------------
template <bool BIN>
__global__ __launch_bounds__(256) void bn_apply_kernel(const u16* __restrict__ src,
                                                       const u16* __restrict__ srcLo,
                                                       int C, int HW,
                                                       const float* __restrict__ st, float cntinv,
                                                       const float* __restrict__ g,
                                                       const float* __restrict__ b,
                                                       float* __restrict__ dout,
                                                       float* __restrict__ dout2,
                                                       u16* __restrict__ act,
                                                       u16* __restrict__ actLo,
                                                       int act_mode) {
    const int t = threadIdx.x;
    const int cl = t & 63, rl = t >> 6;
    const int c = blockIdx.y * 64 + cl;
    const float mean = st[c] * cntinv;
    float var = st[C + c] * cntinv - mean * mean;
    var = fmaxf(var, 0.f);
    const float scale = rsqrtf(var + 1e-5f) * g[c];
    const float shift = b[c] - mean * scale;
    __shared__ float T[64][65];
#pragma unroll
    for (int i = 0; i < 16; i++) {
        int rlocal = rl + i * 4;
        int row = blockIdx.x * 64 + rlocal;
        size_t idx = (size_t)row * C + c;
        float v = BIN ? (float)(short)src[idx] : (bf2f(src[idx]) + bf2f(srcLo[idx]));
        float y = fminf(fmaxf(v * scale + shift, -1.f), 1.f);
        if (act_mode == 1) {
            u16 hi = f2bf(y);
            act[idx] = hi;
            actLo[idx] = lo_bf(y, hi);
        } else if (act_mode == 2) {
            act[idx] = signbf(y);
        }
        T[rlocal][cl] = y;
    }
    __syncthreads();
#pragma unroll
    for (int i = 0; i < 16; i++) {
        int clocal = rl + i * 4;
        int cg = blockIdx.y * 64 + clocal;
        int rglob = blockIdx.x * 64 + cl;
        int n = rglob / HW, hw = rglob % HW;
        size_t o = ((size_t)n * C + cg) * HW + hw;
        float val = T[cl][clocal];
        dout[o] = val;
        if (dout2) dout2[o] = val;
    }
}

// ---------------- FC: [128,8192] @ [10,8192]^T + b (all fp32) ----------------
__global__ __launch_bounds__(256) void fc_kernel(const float* __restrict__ penul,
                                                 const float* __restrict__ fcw,
                                                 const float* __restrict__ fcb,
                                                 float* __restrict__ out) {
    const int t = threadIdx.x, n = blockIdx.x;
    float acc[10];
#pragma unroll
    for (int j = 0; j < 10; j++) acc[j] = 0.f;
    for (int i = t; i < 8192; i += 256) {
        float p = penul[n * 8192 + i];
#pragma unroll
        for (int j = 0; j < 10; j++) acc[j] += p * fcw[j * 8192 + i];
    }
    __shared__ float L[10][256];
#pragma unroll
    for (int j = 0; j < 10; j++) L[j][t] = acc[j];
    __syncthreads();
    for (int s = 128; s > 0; s >>= 1) {
        if (t < s) {
#pragma unroll
            for (int j = 0; j < 10; j++) L[j][t] += L[j][t + s];
        }
        __syncthreads();
    }
    if (t < 10) out[n * 10 + t] = L[t][0] + fcb[t];
}

extern "C" void kernel_launch(void* const* d_in, const int* in_sizes, int n_in,
                              void* d_out, int out_size, void* d_ws, size_t ws_size,
                              hipStream_t stream) {
    (void)in_sizes; (void)n_in; (void)out_size; (void)ws_size;

    const float* X = (const float*)d_in[0];
    const float* W0 = (const float*)d_in[1];
    const float* Wl[5] = {(const float*)d_in[2], (const float*)d_in[3], (const float*)d_in[4],
                          (const float*)d_in[5], (const float*)d_in[6]};
    const float* FCW = (const float*)d_in[7];
    const float* FCB = (const float*)d_in[8];
    const float* G[6]; const float* Bb[6];
    for (int i = 0; i < 6; i++) { G[i] = (const float*)d_in[9 + 2 * i]; Bb[i] = (const float*)d_in[10 + 2 * i]; }

    float* OUT = (float*)d_out;
    char* ws = (char*)d_ws;

    // ws layout (bytes), all disjoint, total 93,329,408 (R6-proven):
    u16* apk   = (u16*)(ws);               // [0,          4,718,592)
    u16* apkLo = (u16*)(ws + 4718592);     // [4,718,592,  9,437,184)
    float* st0 = (float*)(ws + 9437184);   // [9,437,184,  9,439,232)
    float* stk = (float*)(ws + 9439232);   // [9,439,232,  9,443,328)
    u16* F     = (u16*)(ws + 9443328);     // 8,388,608 elems (hi / int16)
    u16* Flo   = (u16*)(ws + 26220544);    // 8,388,608 elems (lo, real)
    u16* AB    = (u16*)(ws + 42997760);    // 8,388,608 elems
    u16* AR    = (u16*)(ws + 59774976);    // 8,388,608 elems
    u16* ARlo  = (u16*)(ws + 76552192);    // 8,388,608 elems

    // Stage-0 arenas:
    //   C0 (fp32 conv0-out, 16,777,216 floats = 67.1MB) lives in ws at the
    //   F..AR range [9,443,328, 76,552,192) — dead until stage 1, exact fit.
    //   Sign acts SG -> d_out O_L3b..O_L4b (dead until stage-3 bn, consumed at
    //   stage-1 bin conv). Real hi/lo -> O_L2b / O_L2r (dead until stage-2 bn).
    float* C0 = (float*)(ws + 9443328);
    u16* SG   = (u16*)(OUT + 26215680);
    u16* X0   = (u16*)(OUT + 9438464);
    u16* X0lo = (u16*)(OUT + 17827072);

    float* O_out = OUT;
    float* O_pen = OUT + 1280;
    float* O_L1b = OUT + 1049856;
    float* O_L1r = OUT + 5244160;
    float* O_L2b = OUT + 9438464;
    float* O_L2r = OUT + 17827072;
    float* O_L3b = OUT + 26215680;
    float* O_L3r = OUT + 28312832;
    float* O_L4b = OUT + 30409984;
    float* O_L4r = OUT + 34604288;
    float* O_L5b = OUT + 38798592;
    float* O_L5r = OUT + 39847168;

    // ---- stage 0: conv0 (1 pass, fp32 -> ws) -> stats -> bn apply (sign + hi/lo)
    conv0_main<<<4096, 256, 0, stream>>>(X, W0, C0);
    hipMemsetAsync(st0, 0, 2048, stream);
    stats0_kernel<<<dim3(2, 256), 256, 0, stream>>>(C0, st0, 128, 512);
    bn0_apply<<<16384, 256, 0, stream>>>(C0, st0, G[0], Bb[0], SG, X0, X0lo);

    struct Stage {
        const float* w; int Cin, Cout, H, W; bool pool;
        dim3 cgrid; dim3 sgrid; int srpb; dim3 bgrid; int bHW; float cntinv;
        float* db; float* dr;
    };
    const Stage S[5] = {
        {Wl[0], 128, 128, 32, 32, true,  dim3(1024, 1), dim3(2, 64), 512, dim3(512, 2), 256, 1.f / 32768.f, O_L1b, O_L1r},
        {Wl[1], 128, 256, 16, 16, false, dim3(256, 2),  dim3(4, 64), 512, dim3(512, 4), 256, 1.f / 32768.f, O_L2b, O_L2r},
        {Wl[2], 256, 256, 16, 16, true,  dim3(256, 2),  dim3(4, 16), 512, dim3(128, 4), 64,  1.f / 8192.f,  O_L3b, O_L3r},
        {Wl[3], 256, 512, 8, 8,   false, dim3(64, 4),   dim3(8, 16), 512, dim3(128, 8), 64,  1.f / 8192.f,  O_L4b, O_L4r},
        {Wl[4], 512, 512, 8, 8,   true,  dim3(64, 4),   dim3(8, 16), 128, dim3(32, 8),  16,  1.f / 2048.f,  O_L5b, O_L5r},
    };

    for (int k = 0; k < 5; k++) {
        const Stage& s = S[k];
        const u16* inB = (k == 0) ? SG : AB;
        const u16* inR = (k == 0) ? X0 : AR;
        const u16* inRlo = (k == 0) ? X0lo : ARlo;

        // ---- binary branch (exact: sign weights/acts, int16 conv-out)
        prepack_kernel<true><<<s.Cout, 256, 0, stream>>>(s.w, apk, nullptr, s.Cin, s.Cout);
        if (s.pool) conv_mfma_kernel<true, true><<<s.cgrid, 256, 0, stream>>>(inB, nullptr, apk, nullptr, F, nullptr, s.Cin, s.Cout, s.H, s.W);
        else        conv_mfma_kernel<false, true><<<s.cgrid, 256, 0, stream>>>(inB, nullptr, apk, nullptr, F, nullptr, s.Cin, s.Cout, s.H, s.W);
        hipMemsetAsync(stk, 0, 4096, stream);
        stats_kernel<true><<<s.sgrid, 256, 0, stream>>>(F, nullptr, stk, s.Cout, s.srpb);
        bn_apply_kernel<true><<<s.bgrid, 256, 0, stream>>>(F, nullptr, s.Cout, s.bHW, stk, s.cntinv,
                                                           G[k + 1], Bb[k + 1], s.db,
                                                           (k == 4) ? O_pen : nullptr,
                                                           AB, nullptr, (k == 4) ? 0 : 2);

        // ---- real branch (3-pass split-bf16; conv-out stored hi+lo)
        prepack_kernel<false><<<s.Cout, 256, 0, stream>>>(s.w, apk, apkLo, s.Cin, s.Cout);
        if (s.pool) conv_mfma_kernel<true, false><<<s.cgrid, 256, 0, stream>>>(inR, inRlo, apk, apkLo, F, Flo, s.Cin, s.Cout, s.H, s.W);
        else        conv_mfma_kernel<false, false><<<s.cgrid, 256, 0, stream>>>(inR, inRlo, apk, apkLo, F, Flo, s.Cin, s.Cout, s.H, s.W);
        hipMemsetAsync(stk, 0, 4096, stream);
        stats_kernel<false><<<s.sgrid, 256, 0, stream>>>(F, Flo, stk, s.Cout, s.srpb);
        bn_apply_kernel<false><<<s.bgrid, 256, 0, stream>>>(F, Flo, s.Cout, s.bHW, stk, s.cntinv,
                                                            G[k + 1], Bb[k + 1], s.dr, nullptr,
                                                            AR, ARlo, (k == 4) ? 0 : 1);
    }

    // ---- fc
    fc_kernel<<<128, 256, 0, stream>>>(O_pen, FCW, FCB, O_out);
}

// Round 9
// 1621.262 us; speedup vs baseline: 2.1819x; 1.1933x over previous
//
#include <hip/hip_runtime.h>

// VGG_SMALL_1W1A on MI355X — R9.
// R8 passed at 1935 us. Top dispatch = stage-1 REAL conv 316 us with
// MfmaUtil 14%, VALUBusy 10%, Occ 12%, HBM 3% -> barrier/staging-bound;
// real branch paid the whole barrier schedule 3x (split-bf16 passes), and
// 64B LDS row stride gave 8-way bank conflicts (SQ_LDS_BANK_CONFLICT 1.4e7).
// R9: (1) real conv merged into ONE traversal: stage Bhi+Blo per cc and
// Whi+Wlo per tap, 48 MFMAs per barrier-pair (terms Whi.Bhi + Whi.Blo +
// Wlo.Bhi, same accumulator); (2) LDS row stride 32->40 u16 (80B) -> b128
// fragment reads tile all 32 banks, conflict-free. Everything else = R8.

typedef unsigned short u16;
typedef __attribute__((ext_vector_type(8))) short short8;
typedef __attribute__((ext_vector_type(8))) unsigned short ushort8;
typedef __attribute__((ext_vector_type(4))) unsigned short ushort4v;
typedef __attribute__((ext_vector_type(4))) float float4v;

__device__ __forceinline__ float bf2f(u16 u) { return __uint_as_float(((unsigned)u) << 16); }
__device__ __forceinline__ u16 f2bf(float f) {
    unsigned u = __float_as_uint(f);
    return (u16)((u + 0x7FFFu + ((u >> 16) & 1u)) >> 16);
}
__device__ __forceinline__ u16 lo_bf(float y, u16 hi) {  // bf16(y - fl(hi))
    return f2bf(y - bf2f(hi));
}
__device__ __forceinline__ u16 signbf(float y) {
    return y > 0.f ? 0x3F80u : (y < 0.f ? 0xBF80u : 0u);
}

// ---------------- conv0_main: 3->128, 32x32, direct fp32, fp32 NHWC out ----------------
__global__ __launch_bounds__(256) void conv0_main(const float* __restrict__ x,
                                                  const float* __restrict__ w0,
                                                  float* __restrict__ out) {
    __shared__ float xt[306];     // [ci][kh][w+2pad], 34-stride rows
    __shared__ float wl[3456];    // 128*27
    const int t = threadIdx.x;
    const int n = blockIdx.x >> 5;
    const int h = blockIdx.x & 31;
    for (int i = t; i < 306; i += 256) xt[i] = 0.f;
    for (int i = t; i < 3456; i += 256) wl[i] = w0[i];
    __syncthreads();
    for (int i = t; i < 288; i += 256) {
        int ci = i / 96; int rr = (i / 32) % 3; int w = i & 31;
        int gh = h - 1 + rr;
        if (gh >= 0 && gh < 32)
            xt[(ci * 3 + rr) * 34 + w + 1] = x[((n * 3 + ci) * 32 + gh) * 32 + w];
    }
    __syncthreads();
    const int w = t & 31, cg = t >> 5;
    float xin[27];
#pragma unroll
    for (int ci = 0; ci < 3; ci++)
#pragma unroll
        for (int r = 0; r < 3; r++)
#pragma unroll
            for (int kw = 0; kw < 3; kw++)
                xin[(ci * 3 + r) * 3 + kw] = xt[(ci * 3 + r) * 34 + w + kw];
    float* o = out + ((size_t)(n * 1024 + h * 32 + w)) * 128 + cg * 16;
#pragma unroll
    for (int jq = 0; jq < 4; jq++) {
        float4v v;
#pragma unroll
        for (int jk = 0; jk < 4; jk++) {
            int co = cg * 16 + jq * 4 + jk;
            float a = 0.f;
#pragma unroll
            for (int e = 0; e < 27; e++) a += xin[e] * wl[co * 27 + e];
            v[jk] = a;
        }
        *(float4v*)(o + jq * 4) = v;
    }
}

// ---------------- stats over fp32 NHWC (stage 0) ----------------
__global__ __launch_bounds__(256) void stats0_kernel(const float* __restrict__ src,
                                                     float* __restrict__ st,
                                                     int C, int rows_per_block) {
    const int t = threadIdx.x;
    const int c = blockIdx.x * 64 + (t & 63);
    const int rg = t >> 6;
    const int r0 = blockIdx.y * rows_per_block;
    float s = 0.f, q = 0.f;
    for (int r = r0 + rg; r < r0 + rows_per_block; r += 4) {
        float v = src[(size_t)r * C + c];
        s += v;
        q += v * v;
    }
    __shared__ float Ls[256], Lq[256];
    Ls[t] = s; Lq[t] = q;
    __syncthreads();
    if (t < 64) {
        s = Ls[t] + Ls[t + 64] + Ls[t + 128] + Ls[t + 192];
        q = Lq[t] + Lq[t + 64] + Lq[t + 128] + Lq[t + 192];
        atomicAdd(&st[c], s);
        atomicAdd(&st[C + c], q);
    }
}

// ---------------- bn0_apply: fp32 conv0-out -> sign acts + real hi/lo acts ----------------
__global__ __launch_bounds__(256) void bn0_apply(const float* __restrict__ src,
                                                 const float* __restrict__ st,
                                                 const float* __restrict__ g,
                                                 const float* __restrict__ b,
                                                 u16* __restrict__ sg,
                                                 u16* __restrict__ hi,
                                                 u16* __restrict__ lo) {
    const int t = threadIdx.x;
    __shared__ float sc[128], sh[128];
    if (t < 128) {
        float mean = st[t] * (1.f / 131072.f);
        float var = fmaxf(st[128 + t] * (1.f / 131072.f) - mean * mean, 0.f);
        float scale = rsqrtf(var + 1e-5f) * g[t];
        sc[t] = scale;
        sh[t] = b[t] - mean * scale;
    }
    __syncthreads();
    size_t i = ((size_t)blockIdx.x * 256 + t) * 4;
    int c0 = (int)(i & 127);
    float4v v = *(const float4v*)(src + i);
    ushort4v hv, lv, sv;
#pragma unroll
    for (int k = 0; k < 4; k++) {
        float y = fminf(fmaxf(v[k] * sc[c0 + k] + sh[c0 + k], -1.f), 1.f);
        hv[k] = f2bf(y);
        lv[k] = lo_bf(y, hv[k]);
        sv[k] = signbf(y);
    }
    *(ushort4v*)(sg + i) = sv;
    *(ushort4v*)(hi + i) = hv;
    *(ushort4v*)(lo + i) = lv;
}

// ---------------- weight prepack; BIN = standardize+sign, else hi+lo split ----------------
template <bool BIN>
__global__ __launch_bounds__(256) void prepack_kernel(const float* __restrict__ w,
                                                      u16* __restrict__ apk,
                                                      u16* __restrict__ apkLo,
                                                      int Cin, int Cout) {
    const int t = threadIdx.x, o = blockIdx.x;
    const int E = Cin * 9;
    float m = 0.f;
    if (BIN) {
        float s = 0.f;
        for (int e = t; e < E; e += 256) s += w[o * E + e];
        __shared__ float Ls[256];
        Ls[t] = s;
        __syncthreads();
        for (int stp = 128; stp > 0; stp >>= 1) {
            if (t < stp) Ls[t] += Ls[t + stp];
            __syncthreads();
        }
        m = Ls[0] / (float)E;
    }
    const int CC = Cin >> 5, COT = Cout >> 7;
    for (int e = t; e < E; e += 256) {
        int ci = e / 9, tap = e % 9;
        float raw = w[o * E + e];
        int idx = ((tap * CC + (ci >> 5)) * COT + (o >> 7)) * 4096 + (o & 127) * 32 + (ci & 31);
        if (BIN) {
            apk[idx] = signbf(raw - m);
        } else {
            u16 hi = f2bf(raw);
            apk[idx] = hi;
            apkLo[idx] = lo_bf(raw, hi);
        }
    }
}

// ---------------- implicit-GEMM MFMA conv ----------------
// BIN: single pass (sign weights/acts, int16 out — exact).
// real: ONE traversal, 3 MFMA terms per tap (Whi.Bhi + Whi.Blo + Wlo.Bhi),
//       out stored as bf16 hi + bf16 lo (fp32-accurate pair).
// LDS rows padded to 40 u16 (80B) -> conflict-free b128 fragment reads.
template <bool POOL, bool BIN>
__global__ __launch_bounds__(256, 2) void conv_mfma_kernel(
    const u16* __restrict__ act, const u16* __restrict__ actLo,
    const u16* __restrict__ apk, const u16* __restrict__ apkLo,
    u16* __restrict__ out, u16* __restrict__ outLo,
    int Cin, int Cout, int H, int W) {
    const int HW = H * W;
    const int t = threadIdx.x;
    const int wave = t >> 6, lane = t & 63;
    const int l15 = lane & 15, quad = lane >> 4;
    const int wm = wave >> 1, wn = wave & 1;

    const int col0 = blockIdx.x * 128;
    const int cot = blockIdx.y;
    const int CC = Cin >> 5;
    const int COT = Cout >> 7;
    const bool two = (HW < 128);          // 128 cols span two images (HW==64)
    const int Wp = W + 2;
    const int nrows = two ? 2 * (H + 2) : (128 / W + 2);
    const int n0 = col0 / HW;
    const int h0 = two ? 0 : (col0 % HW) / W;

    __shared__ __align__(16) u16 AsH[5120];             // [co128][40]
    __shared__ __align__(16) u16 BsH[8160];             // [cell][40]
    __shared__ __align__(16) u16 AsL[BIN ? 16 : 5120];
    __shared__ __align__(16) u16 BsL[BIN ? 16 : 8160];

    int bbase[4], gcol[4];
#pragma unroll
    for (int ni = 0; ni < 4; ni++) {
        int c = wn * 64 + ni * 16 + l15;
        int g = col0 + c;
        int n = g / HW; int hw = g % HW; int h = hw / W; int w = hw % W;
        gcol[ni] = g;
        int rb = two ? ((n - n0) * (H + 2) + h) : (h - h0);
        bbase[ni] = (rb * Wp + w) * 40 + quad * 8;
    }

    float4v acc[4][4];
    const float4v zf = {0.f, 0.f, 0.f, 0.f};
#pragma unroll
    for (int mi = 0; mi < 4; mi++)
#pragma unroll
        for (int ni = 0; ni < 4; ni++) acc[mi][ni] = zf;

    const int bgroups = nrows * Wp * 4;
    const size_t tapstride = (size_t)CC * COT * 4096;
    const int aco = t >> 2;            // A-stage: co handled by this thread
    const int acig = (t & 3) * 8;      // ci offset within chunk

    for (int cc = 0; cc < CC; cc++) {
        __syncthreads();  // protect Bs from previous chunk's readers
        for (int idx = t; idx < bgroups; idx += 256) {
            int cig = idx & 3;
            int rest = idx >> 2;
            int wp = rest % Wp;
            int srow = rest / Wp;
            int n, gh;
            if (two) { n = n0 + srow / (H + 2); gh = srow % (H + 2) - 1; }
            else     { n = n0; gh = h0 + srow - 1; }
            int gw = wp - 1;
            short8 vh = {0, 0, 0, 0, 0, 0, 0, 0};
            short8 vl = {0, 0, 0, 0, 0, 0, 0, 0};
            if (gh >= 0 && gh < H && gw >= 0 && gw < W) {
                size_t goff = ((size_t)(n * HW + gh * W + gw)) * Cin + cc * 32 + cig * 8;
                vh = *(const short8*)(act + goff);
                if (!BIN) vl = *(const short8*)(actLo + goff);
            }
            int loff = (srow * Wp + wp) * 40 + cig * 8;
            *(short8*)&BsH[loff] = vh;
            if (!BIN) *(short8*)&BsL[loff] = vl;
        }
        const u16* abase = apk + ((size_t)(cc * COT + cot)) * 4096;
        const u16* abaseL = apkLo + ((size_t)(cc * COT + cot)) * 4096;
        for (int tap = 0; tap < 9; tap++) {
            __syncthreads();  // protect As; also covers Bs writes before tap 0
            {
                const u16* ab = abase + (size_t)tap * tapstride;
                *(short8*)&AsH[aco * 40 + acig] = *(const short8*)(ab + aco * 32 + acig);
                *(short8*)&AsH[(aco + 64) * 40 + acig] = *(const short8*)(ab + (aco + 64) * 32 + acig);
                if (!BIN) {
                    const u16* abl = abaseL + (size_t)tap * tapstride;
                    *(short8*)&AsL[aco * 40 + acig] = *(const short8*)(abl + aco * 32 + acig);
                    *(short8*)&AsL[(aco + 64) * 40 + acig] = *(const short8*)(abl + (aco + 64) * 32 + acig);
                }
            }
            __syncthreads();
            const int kh = tap / 3, kw = tap % 3;
            const int boff = (kh * Wp + kw) * 40;
            short8 ah[4], bh[4];
#pragma unroll
            for (int mi = 0; mi < 4; mi++)
                ah[mi] = *(const short8*)&AsH[(wm * 64 + mi * 16 + l15) * 40 + quad * 8];
#pragma unroll
            for (int ni = 0; ni < 4; ni++)
                bh[ni] = *(const short8*)&BsH[bbase[ni] + boff];
            if (BIN) {
#pragma unroll
                for (int mi = 0; mi < 4; mi++)
#pragma unroll
                    for (int ni = 0; ni < 4; ni++)
                        acc[mi][ni] = __builtin_amdgcn_mfma_f32_16x16x32_bf16(
                            ah[mi], bh[ni], acc[mi][ni], 0, 0, 0);
            } else {
                short8 al[4], bl[4];
#pragma unroll
                for (int mi = 0; mi < 4; mi++)
                    al[mi] = *(const short8*)&AsL[(wm * 64 + mi * 16 + l15) * 40 + quad * 8];
#pragma unroll
                for (int ni = 0; ni < 4; ni++)
                    bl[ni] = *(const short8*)&BsL[bbase[ni] + boff];
#pragma unroll
                for (int mi = 0; mi < 4; mi++)
#pragma unroll
                    for (int ni = 0; ni < 4; ni++) {
                        acc[mi][ni] = __builtin_amdgcn_mfma_f32_16x16x32_bf16(
                            ah[mi], bh[ni], acc[mi][ni], 0, 0, 0);
                        acc[mi][ni] = __builtin_amdgcn_mfma_f32_16x16x32_bf16(
                            ah[mi], bl[ni], acc[mi][ni], 0, 0, 0);
                        acc[mi][ni] = __builtin_amdgcn_mfma_f32_16x16x32_bf16(
                            al[mi], bh[ni], acc[mi][ni], 0, 0, 0);
                    }
            }
        }
    }

    const int cobase = cot * 128 + wm * 64 + quad * 4;
    // store helper: BIN -> int16 exact; real -> bf16 hi + bf16 lo
    auto store4 = [&](size_t off, float4v v) {
        if (BIN) {
            ushort4v r;
#pragma unroll
            for (int k = 0; k < 4; k++) r[k] = (u16)(short)(int)v[k];
            *(ushort4v*)(out + off) = r;
        } else {
            ushort4v hi, lo;
#pragma unroll
            for (int k = 0; k < 4; k++) {
                hi[k] = f2bf(v[k]);
                lo[k] = lo_bf(v[k], hi[k]);
            }
            *(ushort4v*)(out + off) = hi;
            *(ushort4v*)(outLo + off) = lo;
        }
    };

    if (!POOL) {
#pragma unroll
        for (int mi = 0; mi < 4; mi++)
#pragma unroll
            for (int ni = 0; ni < 4; ni++)
                store4((size_t)gcol[ni] * Cout + cobase + mi * 16, acc[mi][ni]);
    } else {
        const int pH = H >> 1, pW = W >> 1;
        if (W == 32) {
#pragma unroll
            for (int mi = 0; mi < 4; mi++)
#pragma unroll
                for (int nip = 0; nip < 2; nip++) {
                    float4v v;
#pragma unroll
                    for (int k = 0; k < 4; k++)
                        v[k] = fmaxf((float)acc[mi][nip][k], (float)acc[mi][nip + 2][k]);
#pragma unroll
                    for (int k = 0; k < 4; k++) {
                        float vv = v[k];
                        v[k] = fmaxf(vv, __shfl_xor(vv, 1, 64));
                    }
                    if ((l15 & 1) == 0) {
                        int pw = nip * 8 + (l15 >> 1);
                        int ph = (h0 >> 1) + wn;
                        int prow = (n0 * pH + ph) * pW + pw;
                        store4((size_t)prow * Cout + cobase + mi * 16, v);
                    }
                }
        } else if (W == 16) {
#pragma unroll
            for (int mi = 0; mi < 4; mi++)
#pragma unroll
                for (int nip = 0; nip < 4; nip += 2) {
                    float4v v;
#pragma unroll
                    for (int k = 0; k < 4; k++)
                        v[k] = fmaxf((float)acc[mi][nip][k], (float)acc[mi][nip + 1][k]);
#pragma unroll
                    for (int k = 0; k < 4; k++) {
                        float vv = v[k];
                        v[k] = fmaxf(vv, __shfl_xor(vv, 1, 64));
                    }
                    if ((l15 & 1) == 0) {
                        int pw = l15 >> 1;
                        int ph = (h0 + wn * 4 + nip) >> 1;
                        int prow = (n0 * pH + ph) * pW + pw;
                        store4((size_t)prow * Cout + cobase + mi * 16, v);
                    }
                }
        } else {  // W == 8, two-image: n = n0 + wn, h = ni*2 + (l15>>3), w = l15&7
#pragma unroll
            for (int mi = 0; mi < 4; mi++)
#pragma unroll
                for (int ni = 0; ni < 4; ni++) {
                    float4v v = acc[mi][ni];
#pragma unroll
                    for (int k = 0; k < 4; k++) {
                        float vv = v[k];
                        vv = fmaxf(vv, __shfl_xor(vv, 1, 64));
                        v[k] = fmaxf(vv, __shfl_xor(vv, 8, 64));
                    }
                    if ((l15 & 9) == 0) {
                        int pw = l15 >> 1;
                        int ph = ni;
                        int n = n0 + wn;
                        int prow = (n * pH + ph) * pW + pw;
                        store4((size_t)prow * Cout + cobase + mi * 16, v);
                    }
                }
        }
    }
}

// ---------------- per-channel batch stats (sum, sumsq); BIN=int16, real=hi+lo ----------------
template <bool BIN>
__global__ __launch_bounds__(256) void stats_kernel(const u16* __restrict__ src,
                                                    const u16* __restrict__ srcLo,
                                                    float* __restrict__ st,
                                                    int C, int rows_per_block) {
    const int t = threadIdx.x;
    const int c = blockIdx.x * 64 + (t & 63);
    const int rg = t >> 6;
    const int r0 = blockIdx.y * rows_per_block;
    float s = 0.f, q = 0.f;
    for (int r = r0 + rg; r < r0 + rows_per_block; r += 4) {
        size_t i = (size_t)r * C + c;
        float v = BIN ? (float)(short)src[i] : (bf2f(src[i]) + bf2f(srcLo[i]));
        s += v;
        q += v * v;
    }
    __shared__ float Ls[256], Lq[256];
    Ls[t] = s; Lq[t] = q;
    __syncthreads();
    if (t < 64) {
        s = Ls[t] + Ls[t + 64] + Ls[t + 128] + Ls[t + 192];
        q = Lq[t] + Lq[t + 64] + Lq[t + 128] + Lq[t + 192];
        atomicAdd(&st[c], s);
        atomicAdd(&st[C + c], q);
    }
}

// ---------------- BN + hardtanh; acts (mode 1=real hi+lo, 2=sign) + fp32 NCHW d_out ----------------
template <bool BIN>
__global__ __launch_bounds__(256) void bn_apply_kernel(const u16* __restrict__ src,
                                                       const u16* __restrict__ srcLo,
                                                       int C, int HW,
                                                       const float* __restrict__ st, float cntinv,
                                                       const float* __restrict__ g,
                                                       const float* __restrict__ b,
                                                       float* __restrict__ dout,
                                                       float* __restrict__ dout2,
                                                       u16* __restrict__ act,
                                                       u16* __restrict__ actLo,
                                                       int act_mode) {
    const int t = threadIdx.x;
    const int cl = t & 63, rl = t >> 6;
    const int c = blockIdx.y * 64 + cl;
    const float mean = st[c] * cntinv;
    float var = st[C + c] * cntinv - mean * mean;
    var = fmaxf(var, 0.f);
    const float scale = rsqrtf(var + 1e-5f) * g[c];
    const float shift = b[c] - mean * scale;
    __shared__ float T[64][65];
#pragma unroll
    for (int i = 0; i < 16; i++) {
        int rlocal = rl + i * 4;
        int row = blockIdx.x * 64 + rlocal;
        size_t idx = (size_t)row * C + c;
        float v = BIN ? (float)(short)src[idx] : (bf2f(src[idx]) + bf2f(srcLo[idx]));
        float y = fminf(fmaxf(v * scale + shift, -1.f), 1.f);
        if (act_mode == 1) {
            u16 hi = f2bf(y);
            act[idx] = hi;
            actLo[idx] = lo_bf(y, hi);
        } else if (act_mode == 2) {
            act[idx] = signbf(y);
        }
        T[rlocal][cl] = y;
    }
    __syncthreads();
#pragma unroll
    for (int i = 0; i < 16; i++) {
        int clocal = rl + i * 4;
        int cg = blockIdx.y * 64 + clocal;
        int rglob = blockIdx.x * 64 + cl;
        int n = rglob / HW, hw = rglob % HW;
        size_t o = ((size_t)n * C + cg) * HW + hw;
        float val = T[cl][clocal];
        dout[o] = val;
        if (dout2) dout2[o] = val;
    }
}

// ---------------- FC: [128,8192] @ [10,8192]^T + b (all fp32) ----------------
__global__ __launch_bounds__(256) void fc_kernel(const float* __restrict__ penul,
                                                 const float* __restrict__ fcw,
                                                 const float* __restrict__ fcb,
                                                 float* __restrict__ out) {
    const int t = threadIdx.x, n = blockIdx.x;
    float acc[10];
#pragma unroll
    for (int j = 0; j < 10; j++) acc[j] = 0.f;
    for (int i = t; i < 8192; i += 256) {
        float p = penul[n * 8192 + i];
#pragma unroll
        for (int j = 0; j < 10; j++) acc[j] += p * fcw[j * 8192 + i];
    }
    __shared__ float L[10][256];
#pragma unroll
    for (int j = 0; j < 10; j++) L[j][t] = acc[j];
    __syncthreads();
    for (int s = 128; s > 0; s >>= 1) {
        if (t < s) {
#pragma unroll
            for (int j = 0; j < 10; j++) L[j][t] += L[j][t + s];
        }
        __syncthreads();
    }
    if (t < 10) out[n * 10 + t] = L[t][0] + fcb[t];
}

extern "C" void kernel_launch(void* const* d_in, const int* in_sizes, int n_in,
                              void* d_out, int out_size, void* d_ws, size_t ws_size,
                              hipStream_t stream) {
    (void)in_sizes; (void)n_in; (void)out_size; (void)ws_size;

    const float* X = (const float*)d_in[0];
    const float* W0 = (const float*)d_in[1];
    const float* Wl[5] = {(const float*)d_in[2], (const float*)d_in[3], (const float*)d_in[4],
                          (const float*)d_in[5], (const float*)d_in[6]};
    const float* FCW = (const float*)d_in[7];
    const float* FCB = (const float*)d_in[8];
    const float* G[6]; const float* Bb[6];
    for (int i = 0; i < 6; i++) { G[i] = (const float*)d_in[9 + 2 * i]; Bb[i] = (const float*)d_in[10 + 2 * i]; }

    float* OUT = (float*)d_out;
    char* ws = (char*)d_ws;

    // ws layout (bytes), all disjoint, total 93,329,408 (R6-proven):
    u16* apk   = (u16*)(ws);               // [0,          4,718,592)
    u16* apkLo = (u16*)(ws + 4718592);     // [4,718,592,  9,437,184)
    float* st0 = (float*)(ws + 9437184);   // [9,437,184,  9,439,232)
    float* stk = (float*)(ws + 9439232);   // [9,439,232,  9,443,328)
    u16* F     = (u16*)(ws + 9443328);     // 8,388,608 elems (hi / int16)
    u16* Flo   = (u16*)(ws + 26220544);    // 8,388,608 elems (lo, real)
    u16* AB    = (u16*)(ws + 42997760);    // 8,388,608 elems
    u16* AR    = (u16*)(ws + 59774976);    // 8,388,608 elems
    u16* ARlo  = (u16*)(ws + 76552192);    // 8,388,608 elems

    // Stage-0 arenas: C0 in ws (F..AR range, dead until stage 1); sign acts SG
    // and real hi/lo acts in dead d_out regions (R8-proven lifetimes).
    float* C0 = (float*)(ws + 9443328);
    u16* SG   = (u16*)(OUT + 26215680);
    u16* X0   = (u16*)(OUT + 9438464);
    u16* X0lo = (u16*)(OUT + 17827072);

    float* O_out = OUT;
    float* O_pen = OUT + 1280;
    float* O_L1b = OUT + 1049856;
    float* O_L1r = OUT + 5244160;
    float* O_L2b = OUT + 9438464;
    float* O_L2r = OUT + 17827072;
    float* O_L3b = OUT + 26215680;
    float* O_L3r = OUT + 28312832;
    float* O_L4b = OUT + 30409984;
    float* O_L4r = OUT + 34604288;
    float* O_L5b = OUT + 38798592;
    float* O_L5r = OUT + 39847168;

    // ---- stage 0: conv0 (1 pass, fp32 -> ws) -> stats -> bn apply (sign + hi/lo)
    conv0_main<<<4096, 256, 0, stream>>>(X, W0, C0);
    hipMemsetAsync(st0, 0, 2048, stream);
    stats0_kernel<<<dim3(2, 256), 256, 0, stream>>>(C0, st0, 128, 512);
    bn0_apply<<<16384, 256, 0, stream>>>(C0, st0, G[0], Bb[0], SG, X0, X0lo);

    struct Stage {
        const float* w; int Cin, Cout, H, W; bool pool;
        dim3 cgrid; dim3 sgrid; int srpb; dim3 bgrid; int bHW; float cntinv;
        float* db; float* dr;
    };
    const Stage S[5] = {
        {Wl[0], 128, 128, 32, 32, true,  dim3(1024, 1), dim3(2, 64), 512, dim3(512, 2), 256, 1.f / 32768.f, O_L1b, O_L1r},
        {Wl[1], 128, 256, 16, 16, false, dim3(256, 2),  dim3(4, 64), 512, dim3(512, 4), 256, 1.f / 32768.f, O_L2b, O_L2r},
        {Wl[2], 256, 256, 16, 16, true,  dim3(256, 2),  dim3(4, 16), 512, dim3(128, 4), 64,  1.f / 8192.f,  O_L3b, O_L3r},
        {Wl[3], 256, 512, 8, 8,   false, dim3(64, 4),   dim3(8, 16), 512, dim3(128, 8), 64,  1.f / 8192.f,  O_L4b, O_L4r},
        {Wl[4], 512, 512, 8, 8,   true,  dim3(64, 4),   dim3(8, 16), 128, dim3(32, 8),  16,  1.f / 2048.f,  O_L5b, O_L5r},
    };

    for (int k = 0; k < 5; k++) {
        const Stage& s = S[k];
        const u16* inB = (k == 0) ? SG : AB;
        const u16* inR = (k == 0) ? X0 : AR;
        const u16* inRlo = (k == 0) ? X0lo : ARlo;

        // ---- binary branch (exact: sign weights/acts, int16 conv-out)
        prepack_kernel<true><<<s.Cout, 256, 0, stream>>>(s.w, apk, nullptr, s.Cin, s.Cout);
        if (s.pool) conv_mfma_kernel<true, true><<<s.cgrid, 256, 0, stream>>>(inB, nullptr, apk, apk, F, nullptr, s.Cin, s.Cout, s.H, s.W);
        else        conv_mfma_kernel<false, true><<<s.cgrid, 256, 0, stream>>>(inB, nullptr, apk, apk, F, nullptr, s.Cin, s.Cout, s.H, s.W);
        hipMemsetAsync(stk, 0, 4096, stream);
        stats_kernel<true><<<s.sgrid, 256, 0, stream>>>(F, nullptr, stk, s.Cout, s.srpb);
        bn_apply_kernel<true><<<s.bgrid, 256, 0, stream>>>(F, nullptr, s.Cout, s.bHW, stk, s.cntinv,
                                                           G[k + 1], Bb[k + 1], s.db,
                                                           (k == 4) ? O_pen : nullptr,
                                                           AB, nullptr, (k == 4) ? 0 : 2);

        // ---- real branch (single traversal, 3-term split-bf16; out hi+lo)
        prepack_kernel<false><<<s.Cout, 256, 0, stream>>>(s.w, apk, apkLo, s.Cin, s.Cout);
        if (s.pool) conv_mfma_kernel<true, false><<<s.cgrid, 256, 0, stream>>>(inR, inRlo, apk, apkLo, F, Flo, s.Cin, s.Cout, s.H, s.W);
        else        conv_mfma_kernel<false, false><<<s.cgrid, 256, 0, stream>>>(inR, inRlo, apk, apkLo, F, Flo, s.Cin, s.Cout, s.H, s.W);
        hipMemsetAsync(stk, 0, 4096, stream);
        stats_kernel<false><<<s.sgrid, 256, 0, stream>>>(F, Flo, stk, s.Cout, s.srpb);
        bn_apply_kernel<false><<<s.bgrid, 256, 0, stream>>>(F, Flo, s.Cout, s.bHW, stk, s.cntinv,
                                                            G[k + 1], Bb[k + 1], s.dr, nullptr,
                                                            AR, ARlo, (k == 4) ? 0 : 1);
    }

    // ---- fc
    fc_kernel<<<128, 256, 0, stream>>>(O_pen, FCW, FCB, O_out);
}